// Round 7
// baseline (296.174 us; speedup 1.0000x reference)
//
#include <hip/hip_runtime.h>
#include <math.h>

#define NPB 64            // nodes per bucket
#define BSH 6
#define MAXNB 1600
#define BIN_CHUNK 8192
#define HIST_CHUNK 16384

typedef __attribute__((ext_vector_type(8))) short bf16x8;
typedef __attribute__((ext_vector_type(4))) float f32x4;

__device__ __forceinline__ unsigned short f2bf(float f){
  unsigned int u = __float_as_uint(f);
  unsigned int r = (u + 0x7FFFu + ((u >> 16) & 1u)) >> 16;   // RNE
  return (unsigned short)r;
}
__device__ __forceinline__ float bf2f(unsigned int b){
  return __uint_as_float(b << 16);
}
__device__ __forceinline__ float bflo(unsigned int v){ return __uint_as_float(v << 16); }
__device__ __forceinline__ float bfhi(unsigned int v){ return __uint_as_float(v & 0xFFFF0000u); }

// ---------------- CSR build ----------------

__global__ void k_zero(int* __restrict__ p, int n){
  int i = blockIdx.x*256 + threadIdx.x;
  if(i < n) p[i] = 0;
}

__global__ __launch_bounds__(256) void k_bhist(const int* __restrict__ dst, int E,
                                               int* __restrict__ bcnt, int NB){
  __shared__ int l[MAXNB];
  int t = threadIdx.x;
  int base = blockIdx.x*HIST_CHUNK;
  int end = base + HIST_CHUNK; if(end > E) end = E;
  for(int b = t; b < NB; b += 256) l[b] = 0;
  __syncthreads();
  for(int i = base + t; i < end; i += 256) atomicAdd(&l[dst[i] >> BSH], 1);
  __syncthreads();
  for(int b = t; b < NB; b += 256){ int c = l[b]; if(c) atomicAdd(&bcnt[b], c); }
}

__global__ void k_bscan(const int* __restrict__ bcnt, int* __restrict__ bofs,
                        int* __restrict__ bcur, int NB, int E){
  __shared__ int sh[1024];
  int t = threadIdx.x;
  int c0 = (2*t   < NB) ? bcnt[2*t]   : 0;
  int c1 = (2*t+1 < NB) ? bcnt[2*t+1] : 0;
  sh[t] = c0 + c1; __syncthreads();
  for(int off = 1; off < 1024; off <<= 1){
    int v = (t >= off) ? sh[t - off] : 0;
    __syncthreads();
    sh[t] += v;
    __syncthreads();
  }
  int pairEx = sh[t] - (c0 + c1);
  if(2*t   < NB){ bofs[2*t]   = pairEx;      bcur[2*t]   = pairEx; }
  if(2*t+1 < NB){ bofs[2*t+1] = pairEx + c0; bcur[2*t+1] = pairEx + c0; }
  if(t == 0) bofs[NB] = E;
}

__global__ __launch_bounds__(256) void k_binpass(const int* __restrict__ src,
                          const int* __restrict__ dst, int E,
                          int* __restrict__ bcur, unsigned int* __restrict__ binned, int NB){
  __shared__ int lcnt[MAXNB];
  __shared__ int lpos[MAXNB];
  int t = threadIdx.x;
  int base = blockIdx.x * BIN_CHUNK;
  int end = base + BIN_CHUNK; if(end > E) end = E;
  for(int b = t; b < NB; b += 256) lcnt[b] = 0;
  __syncthreads();
  for(int i = base + t; i < end; i += 256)
    atomicAdd(&lcnt[dst[i] >> BSH], 1);
  __syncthreads();
  for(int b = t; b < NB; b += 256){
    int c = lcnt[b];
    lpos[b] = c ? atomicAdd(&bcur[b], c) : 0;
  }
  __syncthreads();
  for(int i = base + t; i < end; i += 256){
    int d = dst[i];
    int b = d >> BSH;
    unsigned int rec = (unsigned int)src[i] | ((unsigned int)(d & (NPB-1)) << 17);
    int p = atomicAdd(&lpos[b], 1);
    binned[p] = rec;
  }
}

__global__ __launch_bounds__(256) void k_bscatter(const unsigned int* __restrict__ binned,
     const int* __restrict__ bofs, int* __restrict__ csr, int* __restrict__ row_ofs,
     float* __restrict__ dinv, int N, int E, int NB){
  __shared__ int lcnt[NPB];
  __shared__ int lofs[NPB];
  __shared__ int lcur[NPB];
  int b = blockIdx.x, t = threadIdx.x;
  int beg = bofs[b], end = bofs[b+1];
  if(t < NPB) lcnt[t] = 0;
  __syncthreads();
  for(int i = beg + t; i < end; i += 256) atomicAdd(&lcnt[binned[i] >> 17], 1);
  __syncthreads();
  if(t < NPB){   // wave 0 only
    int c = lcnt[t];
    int v = c;
    #pragma unroll
    for(int off = 1; off < 64; off <<= 1){
      int nv = __shfl_up(v, off, 64);
      if(t >= off) v += nv;
    }
    int ex = v - c;
    lofs[t] = beg + ex; lcur[t] = 0;
    int node = (b << BSH) + t;
    if(node < N){
      row_ofs[node] = beg + ex;
      dinv[node] = rsqrtf((float)(c + 1));   // +1 self loop
    }
  }
  __syncthreads();
  for(int i = beg + t; i < end; i += 256){
    unsigned int rec = binned[i];
    int dl = rec >> 17;
    int pos = lofs[dl] + atomicAdd(&lcur[dl], 1);
    csr[pos] = (int)(rec & 0x1FFFFu);
  }
  if(b == NB-1 && t == 0) row_ofs[N] = E;
}

// ---------------- GEMM1 (MFMA bf16): g1 = bf16( dinv * (x @ W1) ) ----------------
__global__ __launch_bounds__(256) void k_gemm1(const float* __restrict__ x, const float* __restrict__ W1,
                        const float* __restrict__ dinv, unsigned short* __restrict__ g1, int n){
  __shared__ unsigned short xs[64*136];   // x tile, bf16 [node][k]
  __shared__ unsigned short wt[64*136];   // W1^T,   bf16 [nout][k]
  int tid = threadIdx.x;
  int nodeBase = blockIdx.x*64;
  {
    const float4* x4 = (const float4*)x;
    for(int i = tid; i < 2048; i += 256){
      int node = i >> 5, kg = i & 31;
      float4 v = make_float4(0.f,0.f,0.f,0.f);
      if(nodeBase + node < n) v = x4[(size_t)(nodeBase + node)*32 + kg];
      unsigned p0 = (unsigned)f2bf(v.x) | ((unsigned)f2bf(v.y) << 16);
      unsigned p1 = (unsigned)f2bf(v.z) | ((unsigned)f2bf(v.w) << 16);
      *(uint2*)&xs[node*136 + kg*4] = make_uint2(p0, p1);
    }
  }
  {
    for(int i = tid; i < 2048; i += 256){
      int nn = i >> 5, kq = i & 31;
      unsigned short q0 = f2bf(W1[(kq*4+0)*64 + nn]);
      unsigned short q1 = f2bf(W1[(kq*4+1)*64 + nn]);
      unsigned short q2 = f2bf(W1[(kq*4+2)*64 + nn]);
      unsigned short q3 = f2bf(W1[(kq*4+3)*64 + nn]);
      unsigned p0 = (unsigned)q0 | ((unsigned)q1 << 16);
      unsigned p1 = (unsigned)q2 | ((unsigned)q3 << 16);
      *(uint2*)&wt[nn*136 + kq*4] = make_uint2(p0, p1);
    }
  }
  __syncthreads();

  int w = tid >> 6, lane = tid & 63;
  int ml = lane & 15, q = lane >> 4;
  f32x4 acc0 = {0.f,0.f,0.f,0.f}, acc1 = {0.f,0.f,0.f,0.f},
        acc2 = {0.f,0.f,0.f,0.f}, acc3 = {0.f,0.f,0.f,0.f};
  const unsigned short* arow = &xs[(w*16 + ml)*136 + q*8];
  const unsigned short* brow = &wt[ml*136 + q*8];
  #pragma unroll
  for(int s = 0; s < 4; s++){
    bf16x8 a = *(const bf16x8*)(arow + s*32);
    bf16x8 b0 = *(const bf16x8*)(brow +   0*136 + s*32);
    bf16x8 b1 = *(const bf16x8*)(brow +  16*136 + s*32);
    bf16x8 b2 = *(const bf16x8*)(brow +  32*136 + s*32);
    bf16x8 b3 = *(const bf16x8*)(brow +  48*136 + s*32);
    acc0 = __builtin_amdgcn_mfma_f32_16x16x32_bf16(a, b0, acc0, 0, 0, 0);
    acc1 = __builtin_amdgcn_mfma_f32_16x16x32_bf16(a, b1, acc1, 0, 0, 0);
    acc2 = __builtin_amdgcn_mfma_f32_16x16x32_bf16(a, b2, acc2, 0, 0, 0);
    acc3 = __builtin_amdgcn_mfma_f32_16x16x32_bf16(a, b3, acc3, 0, 0, 0);
  }
  int basem = nodeBase + w*16 + q*4;
  #pragma unroll
  for(int r = 0; r < 4; r++){
    int node = basem + r;
    if(node < n){
      float dv = dinv[node];
      g1[(size_t)node*64 +  0 + ml] = f2bf(acc0[r]*dv);
      g1[(size_t)node*64 + 16 + ml] = f2bf(acc1[r]*dv);
      g1[(size_t)node*64 + 32 + ml] = f2bf(acc2[r]*dv);
      g1[(size_t)node*64 + 48 + ml] = f2bf(acc3[r]*dv);
    }
  }
}

// ---------------- agg1: quarter-gather (4 rows per load), u = bf16(dinv*relu(dinv*sum + b1)) ----------------
// lane = 16q+f; quarter q handles row j+q; lane f reads uint2 #f of the 128-B row.
__global__ __launch_bounds__(256) void k_agg1(const unsigned short* __restrict__ g1,
    const int* __restrict__ row_ofs, const int* __restrict__ csr,
    const float* __restrict__ dinv, const float* __restrict__ b1,
    unsigned short* __restrict__ u, int N){
  int wid = threadIdx.x >> 6, lane = threadIdx.x & 63;
  int q = lane >> 4, f = lane & 15;
  int vq4 = q << 2;
  int node = blockIdx.x*4 + wid;
  if(node >= N) return;
  int beg = row_ofs[node], end = row_ofs[node+1];
  const uint2* g = (const uint2*)g1;
  float a0=0.f, a1=0.f, a2=0.f, a3=0.f;
  if(q == 0){   // self-loop row, counted once
    uint2 v = g[((unsigned)node << 4) + f];
    a0 = bflo(v.x); a1 = bfhi(v.x); a2 = bflo(v.y); a3 = bfhi(v.y);
  }
  for(int e = beg; e < end; e += 64){
    int cnt = end - e; if(cnt > 64) cnt = 64;
    int idx = (lane < cnt) ? csr[e + lane] : 0;
    int j = 0;
    for(; j + 16 <= cnt; j += 16){
      #pragma unroll
      for(int b = 0; b < 16; b += 4){
        int ri = __builtin_amdgcn_ds_bpermute(((j+b) << 2) + vq4, idx);
        uint2 v = g[((unsigned)ri << 4) + f];
        a0 += bflo(v.x); a1 += bfhi(v.x); a2 += bflo(v.y); a3 += bfhi(v.y);
      }
    }
    for(; j < cnt; j += 4){   // 4-row tail granularity: <=3 wasted rows
      int ri = __builtin_amdgcn_ds_bpermute((j << 2) + vq4, idx);
      float w = (j + q < cnt) ? 1.f : 0.f;
      uint2 v = g[((unsigned)ri << 4) + f];
      a0 = fmaf(w, bflo(v.x), a0); a1 = fmaf(w, bfhi(v.x), a1);
      a2 = fmaf(w, bflo(v.y), a2); a3 = fmaf(w, bfhi(v.y), a3);
    }
  }
  a0 += __shfl_xor(a0,16,64); a0 += __shfl_xor(a0,32,64);
  a1 += __shfl_xor(a1,16,64); a1 += __shfl_xor(a1,32,64);
  a2 += __shfl_xor(a2,16,64); a2 += __shfl_xor(a2,32,64);
  a3 += __shfl_xor(a3,16,64); a3 += __shfl_xor(a3,32,64);
  if(q == 0){
    float dv = dinv[node];
    float4 bb = ((const float4*)b1)[f];
    float h0 = fmaxf(fmaf(dv, a0, bb.x), 0.f);
    float h1 = fmaxf(fmaf(dv, a1, bb.y), 0.f);
    float h2 = fmaxf(fmaf(dv, a2, bb.z), 0.f);
    float h3 = fmaxf(fmaf(dv, a3, bb.w), 0.f);
    unsigned p0 = (unsigned)f2bf(dv*h0) | ((unsigned)f2bf(dv*h1) << 16);
    unsigned p1 = (unsigned)f2bf(dv*h2) | ((unsigned)f2bf(dv*h3) << 16);
    ((uint2*)u)[((unsigned)node << 4) + f] = make_uint2(p0, p1);
  }
}

// ---------------- GEMM2: g2 = fp8( u @ W2 ), compact 40-B rows ----------------
// 320 threads: wave = seg (8 feats), lane = node.
__global__ __launch_bounds__(320) void k_gemm2(const unsigned short* __restrict__ u,
                        const float* __restrict__ W2, unsigned char* __restrict__ g2, int n){
  __shared__ float hs[64*65];
  __shared__ float ws[64*40];
  int t = threadIdx.x;
  int nodeBase = blockIdx.x*64;
  for(int i = t; i < 2560; i += 320) ws[i] = W2[i];
  for(int i = t; i < 512; i += 320){
    int row = i >> 3, seg = i & 7;
    uint4 v = make_uint4(0,0,0,0);
    if(nodeBase + row < n) v = *(const uint4*)&u[(size_t)(nodeBase + row)*64 + seg*8];
    float* dp = &hs[row*65 + seg*8];
    dp[0]=bf2f(v.x&0xFFFFu); dp[1]=bf2f(v.x>>16);
    dp[2]=bf2f(v.y&0xFFFFu); dp[3]=bf2f(v.y>>16);
    dp[4]=bf2f(v.z&0xFFFFu); dp[5]=bf2f(v.z>>16);
    dp[6]=bf2f(v.w&0xFFFFu); dp[7]=bf2f(v.w>>16);
  }
  __syncthreads();
  int seg = t >> 6, lane = t & 63;   // seg uniform per wave
  float acc[8] = {0.f,0.f,0.f,0.f,0.f,0.f,0.f,0.f};
  const float* hrow = &hs[lane*65];
  const float* wcol = &ws[seg*8];
  #pragma unroll 4
  for(int k = 0; k < 64; k++){
    float a = hrow[k];
    #pragma unroll
    for(int j = 0; j < 8; j++) acc[j] = fmaf(a, wcol[k*40 + j], acc[j]);
  }
  int node = nodeBase + lane;
  if(node < n){
    int p0 = __builtin_amdgcn_cvt_pk_fp8_f32(acc[0], acc[1], 0, false);
    p0     = __builtin_amdgcn_cvt_pk_fp8_f32(acc[2], acc[3], p0, true);
    int p1 = __builtin_amdgcn_cvt_pk_fp8_f32(acc[4], acc[5], 0, false);
    p1     = __builtin_amdgcn_cvt_pk_fp8_f32(acc[6], acc[7], p1, true);
    *(uint2*)&g2[(size_t)node*40 + seg*8] = make_uint2((unsigned)p0, (unsigned)p1);
  }
}

// ---------------- agg2: quarter-gather fp8 (4 rows/load, 1 dword/lane) + log_softmax ----------------
__global__ __launch_bounds__(256) void k_agg2(const unsigned char* __restrict__ g2,
     const int* __restrict__ row_ofs, const int* __restrict__ csr,
     const float* __restrict__ dinv, const float* __restrict__ b2,
     float* __restrict__ out, int N){
  int wid = threadIdx.x >> 6, lane = threadIdx.x & 63;
  int q = lane >> 4, f = lane & 15;
  int vq4 = q << 2;
  int fc = (f < 10) ? f : 0;    // clamp: f>=10 lanes duplicate dword0, discarded at epilogue
  int node = blockIdx.x*4 + wid;
  if(node >= N) return;
  int beg = row_ofs[node], end = row_ofs[node+1];
  const unsigned* gd = (const unsigned*)g2;   // row = 10 dwords (40 fp8)
  float a0=0.f, a1=0.f, a2=0.f, a3=0.f;
  if(q == 0){   // self row
    unsigned v = gd[(unsigned)node*10 + fc];
    a0 = __builtin_amdgcn_cvt_f32_fp8(v, 0);
    a1 = __builtin_amdgcn_cvt_f32_fp8(v, 1);
    a2 = __builtin_amdgcn_cvt_f32_fp8(v, 2);
    a3 = __builtin_amdgcn_cvt_f32_fp8(v, 3);
  }
  for(int e = beg; e < end; e += 64){
    int cnt = end - e; if(cnt > 64) cnt = 64;
    int idx = (lane < cnt) ? csr[e + lane] : 0;
    int j = 0;
    for(; j + 16 <= cnt; j += 16){
      #pragma unroll
      for(int b = 0; b < 16; b += 4){
        int ri = __builtin_amdgcn_ds_bpermute(((j+b) << 2) + vq4, idx);
        unsigned v = gd[(unsigned)ri*10 + fc];
        a0 += __builtin_amdgcn_cvt_f32_fp8(v, 0);
        a1 += __builtin_amdgcn_cvt_f32_fp8(v, 1);
        a2 += __builtin_amdgcn_cvt_f32_fp8(v, 2);
        a3 += __builtin_amdgcn_cvt_f32_fp8(v, 3);
      }
    }
    for(; j < cnt; j += 4){
      int ri = __builtin_amdgcn_ds_bpermute((j << 2) + vq4, idx);
      float w = (j + q < cnt) ? 1.f : 0.f;
      unsigned v = gd[(unsigned)ri*10 + fc];
      a0 = fmaf(w, __builtin_amdgcn_cvt_f32_fp8(v, 0), a0);
      a1 = fmaf(w, __builtin_amdgcn_cvt_f32_fp8(v, 1), a1);
      a2 = fmaf(w, __builtin_amdgcn_cvt_f32_fp8(v, 2), a2);
      a3 = fmaf(w, __builtin_amdgcn_cvt_f32_fp8(v, 3), a3);
    }
  }
  a0 += __shfl_xor(a0,16,64); a0 += __shfl_xor(a0,32,64);
  a1 += __shfl_xor(a1,16,64); a1 += __shfl_xor(a1,32,64);
  a2 += __shfl_xor(a2,16,64); a2 += __shfl_xor(a2,32,64);
  a3 += __shfl_xor(a3,16,64); a3 += __shfl_xor(a3,32,64);
  bool valid = (q == 0) && (f < 10);
  float dv = dinv[node];
  float4 bb = ((const float4*)b2)[fc];
  float l0 = fmaf(dv, a0, bb.x);
  float l1 = fmaf(dv, a1, bb.y);
  float l2 = fmaf(dv, a2, bb.z);
  float l3 = fmaf(dv, a3, bb.w);
  float m = valid ? fmaxf(fmaxf(l0,l1), fmaxf(l2,l3)) : -INFINITY;
  m = fmaxf(m, __shfl_xor(m,1,64)); m = fmaxf(m, __shfl_xor(m,2,64));
  m = fmaxf(m, __shfl_xor(m,4,64)); m = fmaxf(m, __shfl_xor(m,8,64));
  float ex = valid ? (expf(l0-m)+expf(l1-m)) + (expf(l2-m)+expf(l3-m)) : 0.f;
  ex += __shfl_xor(ex,1,64); ex += __shfl_xor(ex,2,64);
  ex += __shfl_xor(ex,4,64); ex += __shfl_xor(ex,8,64);
  float ll = logf(ex);
  if(valid){
    ((float4*)out)[(unsigned)node*10 + fc] = make_float4(l0-m-ll, l1-m-ll, l2-m-ll, l3-m-ll);
  }
}

// ---------------- launch ----------------

extern "C" void kernel_launch(void* const* d_in, const int* in_sizes, int n_in,
                              void* d_out, int out_size, void* d_ws, size_t ws_size,
                              hipStream_t stream){
  const float* x  = (const float*)d_in[0];
  const int*   ei = (const int*)  d_in[1];
  const float* W1 = (const float*)d_in[2];
  const float* b1 = (const float*)d_in[3];
  const float* W2 = (const float*)d_in[4];
  const float* b2 = (const float*)d_in[5];
  float* out = (float*)d_out;

  int N = in_sizes[0] / 128;        // 100000
  int E = in_sizes[1] / 2;          // 1600000
  const int* src = ei;
  const int* dst = ei + E;
  int NB = (N + NPB - 1) >> BSH;    // 1563

  char* w = (char*)d_ws;
  auto alloc = [&](size_t bytes) -> char* {
    char* p = w;
    w += (bytes + 511) & ~(size_t)511;
    return p;
  };
  int*   bcnt    = (int*)  alloc((size_t)NB*4);
  int*   bofs    = (int*)  alloc((size_t)(NB+1)*4);
  int*   bcur    = (int*)  alloc((size_t)NB*4);
  int*   row_ofs = (int*)  alloc((size_t)(N+1)*4);
  float* dinv    = (float*)alloc((size_t)N*4);
  unsigned int* binned = (unsigned int*)alloc((size_t)E*4);
  int*   csr     = (int*)  alloc((size_t)E*4);
  unsigned short* g1 = (unsigned short*)alloc((size_t)N*64*2);
  unsigned short* u  = (unsigned short*)alloc((size_t)N*64*2);
  unsigned char*  g2 = (unsigned char*) alloc((size_t)N*40);

  k_zero    <<<(NB+255)/256, 256, 0, stream>>>(bcnt, NB);
  k_bhist   <<<(E+HIST_CHUNK-1)/HIST_CHUNK, 256, 0, stream>>>(dst, E, bcnt, NB);
  k_bscan   <<<1, 1024, 0, stream>>>(bcnt, bofs, bcur, NB, E);
  k_binpass <<<(E+BIN_CHUNK-1)/BIN_CHUNK, 256, 0, stream>>>(src, dst, E, bcur, binned, NB);
  k_bscatter<<<NB, 256, 0, stream>>>(binned, bofs, csr, row_ofs, dinv, N, E, NB);

  k_gemm1   <<<(N+63)/64, 256, 0, stream>>>(x, W1, dinv, g1, N);
  k_agg1    <<<(N+3)/4, 256, 0, stream>>>(g1, row_ofs, csr, dinv, b1, u, N);
  k_gemm2   <<<(N+63)/64, 320, 0, stream>>>(u, W2, g2, N);
  k_agg2    <<<(N+3)/4, 256, 0, stream>>>(g2, row_ofs, csr, dinv, b2, out, N);
}

// Round 8
// 290.593 us; speedup vs baseline: 1.0192x; 1.0192x over previous
//
#include <hip/hip_runtime.h>
#include <math.h>

#define NPB 256           // nodes per bucket
#define BSH 8
#define MAXNB 400
#define BIN_CHUNK 8192
#define HIST_CHUNK 16384

typedef __attribute__((ext_vector_type(8))) short bf16x8;
typedef __attribute__((ext_vector_type(4))) float f32x4;
typedef __attribute__((ext_vector_type(2))) float f32x2;

__device__ __forceinline__ unsigned short f2bf(float f){
  unsigned int u = __float_as_uint(f);
  unsigned int r = (u + 0x7FFFu + ((u >> 16) & 1u)) >> 16;   // RNE
  return (unsigned short)r;
}
__device__ __forceinline__ float bf2f(unsigned int b){
  return __uint_as_float(b << 16);
}

// ---------------- CSR build ----------------

__global__ void k_zero(int* __restrict__ p, int n){
  int i = blockIdx.x*256 + threadIdx.x;
  if(i < n) p[i] = 0;
}

__global__ __launch_bounds__(256) void k_bhist(const int* __restrict__ dst, int E,
                                               int* __restrict__ bcnt, int NB){
  __shared__ int l[MAXNB];
  int t = threadIdx.x;
  int base = blockIdx.x*HIST_CHUNK;
  int end = base + HIST_CHUNK; if(end > E) end = E;
  for(int b = t; b < NB; b += 256) l[b] = 0;
  __syncthreads();
  for(int i = base + t; i < end; i += 256) atomicAdd(&l[dst[i] >> BSH], 1);
  __syncthreads();
  for(int b = t; b < NB; b += 256){ int c = l[b]; if(c) atomicAdd(&bcnt[b], c); }
}

__global__ void k_bscan(const int* __restrict__ bcnt, int* __restrict__ bofs,
                        int* __restrict__ bcur, int NB, int E){
  __shared__ int sh[1024];
  int t = threadIdx.x;
  int c0 = (2*t   < NB) ? bcnt[2*t]   : 0;
  int c1 = (2*t+1 < NB) ? bcnt[2*t+1] : 0;
  sh[t] = c0 + c1; __syncthreads();
  for(int off = 1; off < 1024; off <<= 1){
    int v = (t >= off) ? sh[t - off] : 0;
    __syncthreads();
    sh[t] += v;
    __syncthreads();
  }
  int pairEx = sh[t] - (c0 + c1);
  if(2*t   < NB){ bofs[2*t]   = pairEx;      bcur[2*t]   = pairEx; }
  if(2*t+1 < NB){ bofs[2*t+1] = pairEx + c0; bcur[2*t+1] = pairEx + c0; }
  if(t == 0) bofs[NB] = E;
}

__global__ __launch_bounds__(256) void k_binpass(const int* __restrict__ src,
                          const int* __restrict__ dst, int E,
                          int* __restrict__ bcur, unsigned int* __restrict__ binned, int NB){
  __shared__ int lcnt[MAXNB];
  __shared__ int lpos[MAXNB];
  int t = threadIdx.x;
  int base = blockIdx.x * BIN_CHUNK;
  int end = base + BIN_CHUNK; if(end > E) end = E;
  for(int b = t; b < NB; b += 256) lcnt[b] = 0;
  __syncthreads();
  for(int i = base + t; i < end; i += 256)
    atomicAdd(&lcnt[dst[i] >> BSH], 1);
  __syncthreads();
  for(int b = t; b < NB; b += 256){
    int c = lcnt[b];
    lpos[b] = c ? atomicAdd(&bcur[b], c) : 0;
  }
  __syncthreads();
  for(int i = base + t; i < end; i += 256){
    int d = dst[i];
    int b = d >> BSH;
    unsigned int rec = (unsigned int)src[i] | ((unsigned int)(d & (NPB-1)) << 17);
    int p = atomicAdd(&lpos[b], 1);
    binned[p] = rec;
  }
}

// one block per 256-node bucket: LDS hist + 4-wave scan -> row_ofs, dinv, csr
__global__ __launch_bounds__(256) void k_bscatter(const unsigned int* __restrict__ binned,
     const int* __restrict__ bofs, int* __restrict__ csr, int* __restrict__ row_ofs,
     float* __restrict__ dinv, int N, int E, int NB){
  __shared__ int lcnt[NPB];
  __shared__ int lofs[NPB];
  __shared__ int lcur[NPB];
  __shared__ int wsum[4];
  int b = blockIdx.x, t = threadIdx.x;
  int beg = bofs[b], end = bofs[b+1];
  lcnt[t] = 0;
  __syncthreads();
  for(int i = beg + t; i < end; i += 256) atomicAdd(&lcnt[binned[i] >> 17], 1);
  __syncthreads();
  int c = lcnt[t];
  int lane = t & 63, wid = t >> 6;
  int v = c;
  #pragma unroll
  for(int off = 1; off < 64; off <<= 1){
    int nv = __shfl_up(v, off, 64);
    if(lane >= off) v += nv;
  }
  if(lane == 63) wsum[wid] = v;
  __syncthreads();
  int wpre = 0;
  #pragma unroll
  for(int k2 = 0; k2 < 4; k2++) if(k2 < wid) wpre += wsum[k2];
  int ex = wpre + v - c;
  lofs[t] = beg + ex; lcur[t] = 0;
  int node = (b << BSH) + t;
  if(node < N){
    row_ofs[node] = beg + ex;
    dinv[node] = rsqrtf((float)(c + 1));   // +1 self loop
  }
  __syncthreads();
  for(int i = beg + t; i < end; i += 256){
    unsigned int rec = binned[i];
    int dl = rec >> 17;
    int pos = lofs[dl] + atomicAdd(&lcur[dl], 1);
    csr[pos] = (int)(rec & 0x1FFFFu);
  }
  if(b == NB-1 && t == 0) row_ofs[N] = E;
}

// ---------------- GEMM1 (MFMA bf16): g1 = fp8( dinv * (x @ W1) ) ----------------
// A = W1^T (feats as M), B = x (nodes as N) -> lane owns node=ml, 4 contiguous
// feats q*4+r per acc -> packed fp8 dword stores.
__global__ __launch_bounds__(256) void k_gemm1(const float* __restrict__ x, const float* __restrict__ W1,
                        const float* __restrict__ dinv, unsigned int* __restrict__ g1, int n){
  __shared__ unsigned short xs[64*136];   // x tile, bf16 [node][k]
  __shared__ unsigned short wt[64*136];   // W1^T,   bf16 [feat][k]
  int tid = threadIdx.x;
  int nodeBase = blockIdx.x*64;
  {
    const float4* x4 = (const float4*)x;
    for(int i = tid; i < 2048; i += 256){
      int node = i >> 5, kg = i & 31;
      float4 v = make_float4(0.f,0.f,0.f,0.f);
      if(nodeBase + node < n) v = x4[(size_t)(nodeBase + node)*32 + kg];
      unsigned p0 = (unsigned)f2bf(v.x) | ((unsigned)f2bf(v.y) << 16);
      unsigned p1 = (unsigned)f2bf(v.z) | ((unsigned)f2bf(v.w) << 16);
      *(uint2*)&xs[node*136 + kg*4] = make_uint2(p0, p1);
    }
  }
  {
    for(int i = tid; i < 2048; i += 256){
      int nn = i >> 5, kq = i & 31;
      unsigned short q0 = f2bf(W1[(kq*4+0)*64 + nn]);
      unsigned short q1 = f2bf(W1[(kq*4+1)*64 + nn]);
      unsigned short q2 = f2bf(W1[(kq*4+2)*64 + nn]);
      unsigned short q3 = f2bf(W1[(kq*4+3)*64 + nn]);
      unsigned p0 = (unsigned)q0 | ((unsigned)q1 << 16);
      unsigned p1 = (unsigned)q2 | ((unsigned)q3 << 16);
      *(uint2*)&wt[nn*136 + kq*4] = make_uint2(p0, p1);
    }
  }
  __syncthreads();

  int w = tid >> 6, lane = tid & 63;
  int ml = lane & 15, q = lane >> 4;
  f32x4 acc0 = {0.f,0.f,0.f,0.f}, acc1 = {0.f,0.f,0.f,0.f},
        acc2 = {0.f,0.f,0.f,0.f}, acc3 = {0.f,0.f,0.f,0.f};
  const unsigned short* brow = &xs[(w*16 + ml)*136 + q*8];   // B: nodes
  const unsigned short* arow = &wt[ml*136 + q*8];            // A: feats
  #pragma unroll
  for(int s = 0; s < 4; s++){
    bf16x8 bb = *(const bf16x8*)(brow + s*32);
    bf16x8 a0 = *(const bf16x8*)(arow +   0*136 + s*32);
    bf16x8 a1 = *(const bf16x8*)(arow +  16*136 + s*32);
    bf16x8 a2 = *(const bf16x8*)(arow +  32*136 + s*32);
    bf16x8 a3 = *(const bf16x8*)(arow +  48*136 + s*32);
    acc0 = __builtin_amdgcn_mfma_f32_16x16x32_bf16(a0, bb, acc0, 0, 0, 0);
    acc1 = __builtin_amdgcn_mfma_f32_16x16x32_bf16(a1, bb, acc1, 0, 0, 0);
    acc2 = __builtin_amdgcn_mfma_f32_16x16x32_bf16(a2, bb, acc2, 0, 0, 0);
    acc3 = __builtin_amdgcn_mfma_f32_16x16x32_bf16(a3, bb, acc3, 0, 0, 0);
  }
  // D: col = node = ml, row = feat = f*16 + q*4 + r
  int node = nodeBase + w*16 + ml;
  if(node < n){
    float dv = dinv[node];
    unsigned base16 = ((unsigned)node << 4) + q;   // dword index
    int p;
    p = __builtin_amdgcn_cvt_pk_fp8_f32(acc0[0]*dv, acc0[1]*dv, 0, false);
    p = __builtin_amdgcn_cvt_pk_fp8_f32(acc0[2]*dv, acc0[3]*dv, p, true);
    g1[base16 +  0] = (unsigned)p;
    p = __builtin_amdgcn_cvt_pk_fp8_f32(acc1[0]*dv, acc1[1]*dv, 0, false);
    p = __builtin_amdgcn_cvt_pk_fp8_f32(acc1[2]*dv, acc1[3]*dv, p, true);
    g1[base16 +  4] = (unsigned)p;
    p = __builtin_amdgcn_cvt_pk_fp8_f32(acc2[0]*dv, acc2[1]*dv, 0, false);
    p = __builtin_amdgcn_cvt_pk_fp8_f32(acc2[2]*dv, acc2[3]*dv, p, true);
    g1[base16 +  8] = (unsigned)p;
    p = __builtin_amdgcn_cvt_pk_fp8_f32(acc3[0]*dv, acc3[1]*dv, 0, false);
    p = __builtin_amdgcn_cvt_pk_fp8_f32(acc3[2]*dv, acc3[3]*dv, p, true);
    g1[base16 + 12] = (unsigned)p;
  }
}

// ---------------- agg1: quarter-gather fp8 (4 rows/load, 1 dword/lane, packed decode) ----------------
// u = bf16( dinv * relu( dinv*(self + sum) + b1 ) ); lane f owns feats 4f..4f+3
__global__ __launch_bounds__(256) void k_agg1(const unsigned* __restrict__ g1,
    const int* __restrict__ row_ofs, const int* __restrict__ csr,
    const float* __restrict__ dinv, const float* __restrict__ b1,
    unsigned short* __restrict__ u, int N){
  int wid = threadIdx.x >> 6, lane = threadIdx.x & 63;
  int q = lane >> 4, f = lane & 15;
  int vq4 = q << 2;
  int node = blockIdx.x*4 + wid;
  if(node >= N) return;
  int beg = row_ofs[node], end = row_ofs[node+1];
  f32x2 s01 = {0.f,0.f}, s23 = {0.f,0.f};
  if(q == 0){   // self row, counted once
    unsigned v = g1[((unsigned)node << 4) + f];
    s01 = __builtin_amdgcn_cvt_pk_f32_fp8(v, false);
    s23 = __builtin_amdgcn_cvt_pk_f32_fp8(v, true);
  }
  for(int e = beg; e < end; e += 64){
    int cnt = end - e; if(cnt > 64) cnt = 64;
    int idx = (lane < cnt) ? csr[e + lane] : 0;
    int j = 0;
    for(; j + 16 <= cnt; j += 16){
      #pragma unroll
      for(int b = 0; b < 16; b += 4){
        int ri = __builtin_amdgcn_ds_bpermute(((j+b) << 2) + vq4, idx);
        unsigned v = g1[((unsigned)ri << 4) + f];
        s01 += __builtin_amdgcn_cvt_pk_f32_fp8(v, false);
        s23 += __builtin_amdgcn_cvt_pk_f32_fp8(v, true);
      }
    }
    for(; j < cnt; j += 4){
      int ri = __builtin_amdgcn_ds_bpermute((j << 2) + vq4, idx);
      float w = (j + q < cnt) ? 1.f : 0.f;
      unsigned v = g1[((unsigned)ri << 4) + f];
      f32x2 p0 = __builtin_amdgcn_cvt_pk_f32_fp8(v, false);
      f32x2 p1 = __builtin_amdgcn_cvt_pk_f32_fp8(v, true);
      s01 += p0*w; s23 += p1*w;
    }
  }
  s01.x += __shfl_xor(s01.x,16,64); s01.x += __shfl_xor(s01.x,32,64);
  s01.y += __shfl_xor(s01.y,16,64); s01.y += __shfl_xor(s01.y,32,64);
  s23.x += __shfl_xor(s23.x,16,64); s23.x += __shfl_xor(s23.x,32,64);
  s23.y += __shfl_xor(s23.y,16,64); s23.y += __shfl_xor(s23.y,32,64);
  if(q == 0){
    float dv = dinv[node];
    float4 bb = ((const float4*)b1)[f];
    float h0 = fmaxf(fmaf(dv, s01.x, bb.x), 0.f);
    float h1 = fmaxf(fmaf(dv, s01.y, bb.y), 0.f);
    float h2 = fmaxf(fmaf(dv, s23.x, bb.z), 0.f);
    float h3 = fmaxf(fmaf(dv, s23.y, bb.w), 0.f);
    unsigned p0 = (unsigned)f2bf(dv*h0) | ((unsigned)f2bf(dv*h1) << 16);
    unsigned p1 = (unsigned)f2bf(dv*h2) | ((unsigned)f2bf(dv*h3) << 16);
    ((uint2*)u)[((unsigned)node << 4) + f] = make_uint2(p0, p1);
  }
}

// ---------------- GEMM2: g2 = fp8( u @ W2 ), compact 40-B rows ----------------
__global__ __launch_bounds__(320) void k_gemm2(const unsigned short* __restrict__ u,
                        const float* __restrict__ W2, unsigned char* __restrict__ g2, int n){
  __shared__ float hs[64*65];
  __shared__ float ws[64*40];
  int t = threadIdx.x;
  int nodeBase = blockIdx.x*64;
  for(int i = t; i < 2560; i += 320) ws[i] = W2[i];
  for(int i = t; i < 512; i += 320){
    int row = i >> 3, seg = i & 7;
    uint4 v = make_uint4(0,0,0,0);
    if(nodeBase + row < n) v = *(const uint4*)&u[(size_t)(nodeBase + row)*64 + seg*8];
    float* dp = &hs[row*65 + seg*8];
    dp[0]=bf2f(v.x&0xFFFFu); dp[1]=bf2f(v.x>>16);
    dp[2]=bf2f(v.y&0xFFFFu); dp[3]=bf2f(v.y>>16);
    dp[4]=bf2f(v.z&0xFFFFu); dp[5]=bf2f(v.z>>16);
    dp[6]=bf2f(v.w&0xFFFFu); dp[7]=bf2f(v.w>>16);
  }
  __syncthreads();
  int seg = t >> 6, lane = t & 63;   // seg uniform per wave
  float acc[8] = {0.f,0.f,0.f,0.f,0.f,0.f,0.f,0.f};
  const float* hrow = &hs[lane*65];
  const float* wcol = &ws[seg*8];
  #pragma unroll 4
  for(int k = 0; k < 64; k++){
    float a = hrow[k];
    #pragma unroll
    for(int j = 0; j < 8; j++) acc[j] = fmaf(a, wcol[k*40 + j], acc[j]);
  }
  int node = nodeBase + lane;
  if(node < n){
    int p0 = __builtin_amdgcn_cvt_pk_fp8_f32(acc[0], acc[1], 0, false);
    p0     = __builtin_amdgcn_cvt_pk_fp8_f32(acc[2], acc[3], p0, true);
    int p1 = __builtin_amdgcn_cvt_pk_fp8_f32(acc[4], acc[5], 0, false);
    p1     = __builtin_amdgcn_cvt_pk_fp8_f32(acc[6], acc[7], p1, true);
    *(uint2*)&g2[(size_t)node*40 + seg*8] = make_uint2((unsigned)p0, (unsigned)p1);
  }
}

// ---------------- agg2: quarter-gather fp8 packed + bias + log_softmax ----------------
__global__ __launch_bounds__(256) void k_agg2(const unsigned char* __restrict__ g2,
     const int* __restrict__ row_ofs, const int* __restrict__ csr,
     const float* __restrict__ dinv, const float* __restrict__ b2,
     float* __restrict__ out, int N){
  int wid = threadIdx.x >> 6, lane = threadIdx.x & 63;
  int q = lane >> 4, f = lane & 15;
  int vq4 = q << 2;
  int fc = (f < 10) ? f : 0;    // f>=10 lanes duplicate dword0, discarded
  int node = blockIdx.x*4 + wid;
  if(node >= N) return;
  int beg = row_ofs[node], end = row_ofs[node+1];
  const unsigned* gd = (const unsigned*)g2;   // row = 10 dwords (40 fp8)
  f32x2 s01 = {0.f,0.f}, s23 = {0.f,0.f};
  if(q == 0){   // self row
    unsigned v = gd[(unsigned)node*10 + fc];
    s01 = __builtin_amdgcn_cvt_pk_f32_fp8(v, false);
    s23 = __builtin_amdgcn_cvt_pk_f32_fp8(v, true);
  }
  for(int e = beg; e < end; e += 64){
    int cnt = end - e; if(cnt > 64) cnt = 64;
    int idx = (lane < cnt) ? csr[e + lane] : 0;
    int j = 0;
    for(; j + 16 <= cnt; j += 16){
      #pragma unroll
      for(int b = 0; b < 16; b += 4){
        int ri = __builtin_amdgcn_ds_bpermute(((j+b) << 2) + vq4, idx);
        unsigned v = gd[(unsigned)ri*10 + fc];
        s01 += __builtin_amdgcn_cvt_pk_f32_fp8(v, false);
        s23 += __builtin_amdgcn_cvt_pk_f32_fp8(v, true);
      }
    }
    for(; j < cnt; j += 4){
      int ri = __builtin_amdgcn_ds_bpermute((j << 2) + vq4, idx);
      float w = (j + q < cnt) ? 1.f : 0.f;
      unsigned v = gd[(unsigned)ri*10 + fc];
      f32x2 p0 = __builtin_amdgcn_cvt_pk_f32_fp8(v, false);
      f32x2 p1 = __builtin_amdgcn_cvt_pk_f32_fp8(v, true);
      s01 += p0*w; s23 += p1*w;
    }
  }
  s01.x += __shfl_xor(s01.x,16,64); s01.x += __shfl_xor(s01.x,32,64);
  s01.y += __shfl_xor(s01.y,16,64); s01.y += __shfl_xor(s01.y,32,64);
  s23.x += __shfl_xor(s23.x,16,64); s23.x += __shfl_xor(s23.x,32,64);
  s23.y += __shfl_xor(s23.y,16,64); s23.y += __shfl_xor(s23.y,32,64);
  bool valid = (q == 0) && (f < 10);
  float dv = dinv[node];
  float4 bb = ((const float4*)b2)[fc];
  float l0 = fmaf(dv, s01.x, bb.x);
  float l1 = fmaf(dv, s01.y, bb.y);
  float l2 = fmaf(dv, s23.x, bb.z);
  float l3 = fmaf(dv, s23.y, bb.w);
  float m = valid ? fmaxf(fmaxf(l0,l1), fmaxf(l2,l3)) : -INFINITY;
  m = fmaxf(m, __shfl_xor(m,1,64)); m = fmaxf(m, __shfl_xor(m,2,64));
  m = fmaxf(m, __shfl_xor(m,4,64)); m = fmaxf(m, __shfl_xor(m,8,64));
  float ex = valid ? (expf(l0-m)+expf(l1-m)) + (expf(l2-m)+expf(l3-m)) : 0.f;
  ex += __shfl_xor(ex,1,64); ex += __shfl_xor(ex,2,64);
  ex += __shfl_xor(ex,4,64); ex += __shfl_xor(ex,8,64);
  float ll = logf(ex);
  if(valid){
    ((float4*)out)[(unsigned)node*10 + fc] = make_float4(l0-m-ll, l1-m-ll, l2-m-ll, l3-m-ll);
  }
}

// ---------------- launch ----------------

extern "C" void kernel_launch(void* const* d_in, const int* in_sizes, int n_in,
                              void* d_out, int out_size, void* d_ws, size_t ws_size,
                              hipStream_t stream){
  const float* x  = (const float*)d_in[0];
  const int*   ei = (const int*)  d_in[1];
  const float* W1 = (const float*)d_in[2];
  const float* b1 = (const float*)d_in[3];
  const float* W2 = (const float*)d_in[4];
  const float* b2 = (const float*)d_in[5];
  float* out = (float*)d_out;

  int N = in_sizes[0] / 128;        // 100000
  int E = in_sizes[1] / 2;          // 1600000
  const int* src = ei;
  const int* dst = ei + E;
  int NB = (N + NPB - 1) >> BSH;    // 391

  char* w = (char*)d_ws;
  auto alloc = [&](size_t bytes) -> char* {
    char* p = w;
    w += (bytes + 511) & ~(size_t)511;
    return p;
  };
  int*   bcnt    = (int*)  alloc((size_t)NB*4);
  int*   bofs    = (int*)  alloc((size_t)(NB+1)*4);
  int*   bcur    = (int*)  alloc((size_t)NB*4);
  int*   row_ofs = (int*)  alloc((size_t)(N+1)*4);
  float* dinv    = (float*)alloc((size_t)N*4);
  unsigned int* binned = (unsigned int*)alloc((size_t)E*4);
  int*   csr     = (int*)  alloc((size_t)E*4);
  unsigned int*   g1 = (unsigned int*)  alloc((size_t)N*64);   // fp8, 64 B rows
  unsigned short* u  = (unsigned short*)alloc((size_t)N*64*2); // bf16
  unsigned char*  g2 = (unsigned char*) alloc((size_t)N*40);   // fp8, 40 B rows

  k_zero    <<<(NB+255)/256, 256, 0, stream>>>(bcnt, NB);
  k_bhist   <<<(E+HIST_CHUNK-1)/HIST_CHUNK, 256, 0, stream>>>(dst, E, bcnt, NB);
  k_bscan   <<<1, 1024, 0, stream>>>(bcnt, bofs, bcur, NB, E);
  k_binpass <<<(E+BIN_CHUNK-1)/BIN_CHUNK, 256, 0, stream>>>(src, dst, E, bcur, binned, NB);
  k_bscatter<<<NB, 256, 0, stream>>>(binned, bofs, csr, row_ofs, dinv, N, E, NB);

  k_gemm1   <<<(N+63)/64, 256, 0, stream>>>(x, W1, dinv, g1, N);
  k_agg1    <<<(N+3)/4, 256, 0, stream>>>(g1, row_ofs, csr, dinv, b1, u, N);
  k_gemm2   <<<(N+63)/64, 320, 0, stream>>>(u, W2, g2, N);
  k_agg2    <<<(N+3)/4, 256, 0, stream>>>(g2, row_ofs, csr, dinv, b2, out, N);
}